// Round 11
// baseline (28.270 us; speedup 1.0000x reference)
//
#include <hip/hip_runtime.h>

// Tensorized (tensor-train) embedding. vocab 32000 = 8*10*20*20, out 768,
// ranks (1,16,16,16,1), B = 32768 tokens, fp32 out.
//
// Per token: out[a][mc] = sum_r2 G01[c01][a][r2] * G23[c23][r2][mc]
//   (c01 = idx/400, c23 = idx%400) -- a 16x16 @ 16x48 matmul, done as
// 3x mfma_f32_16x16x16f16 (K=16 exact) on pre-swizzled f16 fragment
// tables (A = G2^T chunks, B = G1^T), transposed-tile orientation so each
// lane's 4 accs are 4 consecutive mc of one output row.
//
// R11 vs R10: TPW 8->16 (512 blocks; half the wave prologues), A01+A2
// merged into one 32B record (one base addr, one 2KB stream per c23),
// G23 build split across 800 blocks (mc 0..31 / 32..47 halves, matching
// the record split) to cut build latency.
//
// Fragment maps (gfx950): A[m][k]: lane l holds m=l&15, k=(l>>4)*4+j
// (j=0..3); B[k][n]: n=l&15, same k-map (A/B symmetric -> builder's
// k-permutation cancels). D[m][n]: lane l reg r: m=(l>>4)*4+r, n=l&15.

#define NTOK 32768
#define TPW  16
#define NBLK (NTOK / (4 * TPW))               // 512
#define G2REC_BYTES (400 * 64 * 32)           // 819200: [A01 16B|A2 8B|pad 8B]
#define G1B_BYTES   (80 * 64 * 8)             // 40960
#define TBL_BYTES   (G2REC_BYTES + G1B_BYTES) // 860160

typedef _Float16 f16x4 __attribute__((ext_vector_type(4)));
typedef _Float16 f16x8 __attribute__((ext_vector_type(8)));
typedef float f32x4 __attribute__((ext_vector_type(4)));

__device__ inline unsigned pack2(float x, float y) {
    _Float16 hx = (_Float16)x, hy = (_Float16)y;
    unsigned short ux = __builtin_bit_cast(unsigned short, hx);
    unsigned short uy = __builtin_bit_cast(unsigned short, hy);
    return (unsigned)ux | ((unsigned)uy << 16);
}

// ---- kernel A: build f16 fragment tables (880 blocks) ----
// blocks 0..799: G23 (2 per c23: half 0 -> mc 0..31 + A01, half 1 -> mc 32..47 + A2)
// blocks 800..879: G01 -> B records
__global__ __launch_bounds__(256) void build_frag_tables(const float* __restrict__ core0,
                                                         const float* __restrict__ core1,
                                                         const float* __restrict__ core2,
                                                         const float* __restrict__ core3,
                                                         unsigned* __restrict__ g2rec,
                                                         unsigned* __restrict__ g1b) {
    __shared__ float lds[768];              // indexed r2*48+mc (sparse fill per half)
    int b = blockIdx.x, t = threadIdx.x;
    int l = t & 63, part = t >> 6;          // lane 0..63, part 0..3
    if (b < 800) {
        int c23 = b >> 1, half = b & 1;
        int d2 = c23 / 20, d3 = c23 % 20;
        // half 0: mc 0..31 (512 vals, 2 iters); half 1: mc 32..47 (256 vals, 1 iter)
        int niter = half ? 1 : 2;
#pragma unroll
        for (int i = 0; i < 2; ++i) {
            if (i >= niter) break;
            int v = t + i * 256;            // value id within this half
            int mcw = half ? 16 : 32;       // mc width of this half
            int r2 = v / mcw;
            int mc = (half ? 32 : 0) + (v - r2 * mcw);
            int m2 = mc >> 3, m3 = mc & 7;
            float acc = 0.f;
#pragma unroll
            for (int r3 = 0; r3 < 16; ++r3)
                acc += core2[((r2 * 20 + d2) * 6 + m2) * 16 + r3] *   // [16,20,6,16]
                       core3[(r3 * 20 + d3) * 8 + m3];                // [16,20,8,1]
            lds[r2 * 48 + mc] = acc;
        }
        __syncthreads();
        unsigned* rec = g2rec + (size_t)c23 * 512 + l * 8;  // 8 u32 per lane
        if (half == 0) {                    // A01: words 0..3 (chunk pp, k-pair jp)
            int pp = part >> 1, jp = part & 1;
            int k = ((l >> 4) << 2) + jp * 2;
            int mc = pp * 16 + (l & 15);
            rec[part] = pack2(lds[k * 48 + mc], lds[(k + 1) * 48 + mc]);
        } else if (part < 2) {              // A2: words 4..5 (mc 32..47)
            int k = ((l >> 4) << 2) + part * 2;
            int mc = 32 + (l & 15);
            rec[4 + part] = pack2(lds[k * 48 + mc], lds[(k + 1) * 48 + mc]);
        }
    } else {                                // G01 combo c01 = d0*10+d1
        int combo = b - 800;                // 0..79
        int d0 = combo / 10, d1 = combo % 10;
        int a = t >> 4, r2 = t & 15;
        int a0 = a >> 2, m1 = a & 3;
        float acc = 0.f;
#pragma unroll
        for (int r1 = 0; r1 < 16; ++r1)
            acc += core0[(d0 * 4 + a0) * 16 + r1] *                   // [1,8,4,16]
                   core1[((r1 * 10 + d1) * 4 + m1) * 16 + r2];        // [16,10,4,16]
        lds[t] = acc;                       // lds[a*16 + r2]
        __syncthreads();
        if (part < 2) {                     // B record: 2 u32/lane
            int k = ((l >> 4) << 2) + part * 2;   // r2
            int n = l & 15;                       // a
            g1b[(combo * 64 + l) * 2 + part] = pack2(lds[n * 16 + k],
                                                     lds[n * 16 + k + 1]);
        }
    }
}

// ---- kernel B: MFMA main, zero LDS, depth-2 prefetch ----
struct Frag { f16x8 a01; f16x4 a2; f16x4 b; };

__device__ inline Frag load_frag(int id, int lane,
                                 const unsigned* __restrict__ g2rec,
                                 const f16x4* __restrict__ g1b) {
    Frag f;
    int c23 = id % 400, c01 = id / 400;
    const unsigned* rec = g2rec + (size_t)c23 * 512 + lane * 8;
    f.a01 = *(const f16x8*)rec;             // 16B
    f.a2  = *(const f16x4*)(rec + 4);       // 8B, same base
    f.b   = g1b[c01 * 64 + lane];           // 8B
    return f;
}

__global__ __launch_bounds__(256) void te_mfma(const int* __restrict__ x,
                                               const unsigned* __restrict__ g2rec,
                                               const f16x4* __restrict__ g1b,
                                               float* __restrict__ out) {
    const int wave = threadIdx.x >> 6, lane = threadIdx.x & 63;
    const int tok0 = (blockIdx.x * 4 + wave) * TPW;

    int idxs[TPW];
#pragma unroll
    for (int i = 0; i < TPW / 4; ++i) {
        int4 xv = ((const int4*)(x + tok0))[i];
        idxs[i * 4 + 0] = xv.x; idxs[i * 4 + 1] = xv.y;
        idxs[i * 4 + 2] = xv.z; idxs[i * 4 + 3] = xv.w;
    }

    Frag f0 = load_frag(idxs[0], lane, g2rec, g1b);
    Frag f1 = load_frag(idxs[1], lane, g2rec, g1b);

    const f32x4 z = {0.f, 0.f, 0.f, 0.f};
    float* obase = out + (size_t)tok0 * 768 + (lane & 15) * 48 + ((lane >> 4) << 2);

#pragma unroll
    for (int t = 0; t < TPW; ++t) {
        Frag f2 = f1;
        if (t + 2 < TPW)                    // depth-2 prefetch
            f2 = load_frag(idxs[t + 2], lane, g2rec, g1b);

        f16x4 a0 = __builtin_shufflevector(f0.a01, f0.a01, 0, 1, 2, 3);
        f16x4 a1 = __builtin_shufflevector(f0.a01, f0.a01, 4, 5, 6, 7);
        f32x4 d0 = __builtin_amdgcn_mfma_f32_16x16x16f16(a0,    f0.b, z, 0, 0, 0);
        f32x4 d1 = __builtin_amdgcn_mfma_f32_16x16x16f16(a1,    f0.b, z, 0, 0, 0);
        f32x4 d2 = __builtin_amdgcn_mfma_f32_16x16x16f16(f0.a2, f0.b, z, 0, 0, 0);

        float* o = obase + t * 768;
        *(f32x4*)(o)      = d0;             // mc chunk 0
        *(f32x4*)(o + 16) = d1;             // mc chunk 1
        *(f32x4*)(o + 32) = d2;             // mc chunk 2

        f0 = f1; f1 = f2;
    }
}

// ---- fallback (tiny ws): direct evaluation ----
__global__ void te_direct(const int* __restrict__ x,
                          const float* __restrict__ core0,
                          const float* __restrict__ core1,
                          const float* __restrict__ core2,
                          const float* __restrict__ core3,
                          float* __restrict__ out) {
    int tok = blockIdx.x;
    int lane = threadIdx.x;
    int idx = x[tok];
    int d0 = idx / 4000;
    int rem = idx - d0 * 4000;
    int d1 = rem / 400;
    rem -= d1 * 400;
    int d2 = rem / 20;
    int d3 = rem - d2 * 20;
    float* o = out + (size_t)tok * 768;
    for (int p = 0; p < 3; ++p) {
        int base = (p * 64 + lane) * 4;
        int a = base / 48;
        int mc = base - a * 48;
        int a0 = a >> 2, m1 = a & 3;
        float s[16];
#pragma unroll
        for (int r2 = 0; r2 < 16; ++r2) {
            float acc = 0.f;
            for (int r1 = 0; r1 < 16; ++r1)
                acc += core0[(d0 * 4 + a0) * 16 + r1] *
                       core1[((r1 * 10 + d1) * 4 + m1) * 16 + r2];
            s[r2] = acc;
        }
        float4 accv = {0.f, 0.f, 0.f, 0.f};
        float* accp = (float*)&accv;
        for (int j = 0; j < 4; ++j) {
            int mcj = mc + j;
            int m2 = mcj >> 3, m3 = mcj & 7;
            float tt = 0.f;
            for (int r2 = 0; r2 < 16; ++r2) {
                float g = 0.f;
                for (int r3 = 0; r3 < 16; ++r3)
                    g += core2[((r2 * 20 + d2) * 6 + m2) * 16 + r3] *
                         core3[(r3 * 20 + d3) * 8 + m3];
                tt += s[r2] * g;
            }
            accp[j] = tt;
        }
        *(float4*)(o + base) = accv;
    }
}

extern "C" void kernel_launch(void* const* d_in, const int* in_sizes, int n_in,
                              void* d_out, int out_size, void* d_ws, size_t ws_size,
                              hipStream_t stream) {
    const int*   x     = (const int*)d_in[0];
    const float* core0 = (const float*)d_in[1];
    const float* core1 = (const float*)d_in[2];
    const float* core2 = (const float*)d_in[3];
    const float* core3 = (const float*)d_in[4];
    float* out = (float*)d_out;

    if (ws_size >= (size_t)TBL_BYTES) {
        unsigned* g2rec = (unsigned*)d_ws;
        unsigned* g1b   = (unsigned*)((char*)d_ws + G2REC_BYTES);
        build_frag_tables<<<880, 256, 0, stream>>>(core0, core1, core2, core3,
                                                   g2rec, g1b);
        // 512 blocks x 4 waves x 16 tokens = 32768 exactly
        te_mfma<<<NBLK, 256, 0, stream>>>(x, g2rec, (const f16x4*)g1b, out);
    } else {
        te_direct<<<NTOK, 64, 0, stream>>>(x, core0, core1, core2, core3, out);
    }
}

// Round 12
// 27.739 us; speedup vs baseline: 1.0191x; 1.0191x over previous
//
#include <hip/hip_runtime.h>

// Tensorized (tensor-train) embedding. vocab 32000 = 8*10*20*20, out 768,
// ranks (1,16,16,16,1), B = 32768 tokens, fp32 out.
//
// Per token: out[a][mc] = sum_r2 G01[c01][a][r2] * G23[c23][r2][mc]
//   (c01 = idx/400, c23 = idx%400) -- a 16x16 @ 16x48 matmul, done as
// 3x mfma_f32_16x16x16f16 (K=16 exact) on pre-swizzled f16 fragment
// tables (A = G2^T chunks, B = G1^T), transposed-tile orientation so each
// lane's 4 accs are 4 consecutive mc of one output row.
//
// R12 = R10 (best, 27.7us) + prefetch depth 3 (ring of named frags).
// Rationale: unified in-order vmcnt retires loads behind store drain;
// deeper issue-to-use distance raises tolerated outstanding ops in the
// compiler's s_waitcnt, decoupling fragment-load waits from HBM-paced
// stores. R11's TPW=16/merged-record/split-build all reverted (28.3 > 27.7).
//
// Fragment maps (gfx950): A[m][k]: lane l holds m=l&15, k=(l>>4)*4+j
// (j=0..3); B[k][n]: n=l&15, same k-map (A/B symmetric -> builder's
// k-permutation cancels). D[m][n]: lane l reg r: m=(l>>4)*4+r, n=l&15.

#define NTOK 32768
#define TPW  8
#define NBLK (NTOK / (4 * TPW))               // 1024
#define G2A01_BYTES (400 * 64 * 16)           // 409600
#define G2A2_BYTES  (400 * 64 * 8)            // 204800
#define G1B_BYTES   (80 * 64 * 8)             // 40960
#define TBL_BYTES   (G2A01_BYTES + G2A2_BYTES + G1B_BYTES)  // 655360

typedef _Float16 f16x4 __attribute__((ext_vector_type(4)));
typedef _Float16 f16x8 __attribute__((ext_vector_type(8)));
typedef float f32x4 __attribute__((ext_vector_type(4)));

__device__ inline unsigned pack2(float x, float y) {
    _Float16 hx = (_Float16)x, hy = (_Float16)y;
    unsigned short ux = __builtin_bit_cast(unsigned short, hx);
    unsigned short uy = __builtin_bit_cast(unsigned short, hy);
    return (unsigned)ux | ((unsigned)uy << 16);
}

// ---- kernel A: build f16 fragment tables (480 blocks) ----
__global__ __launch_bounds__(256) void build_frag_tables(const float* __restrict__ core0,
                                                         const float* __restrict__ core1,
                                                         const float* __restrict__ core2,
                                                         const float* __restrict__ core3,
                                                         unsigned* __restrict__ g2a01,
                                                         unsigned* __restrict__ g2a2,
                                                         unsigned* __restrict__ g1b) {
    __shared__ float lds[768];
    int b = blockIdx.x, t = threadIdx.x;
    int l = t & 63, part = t >> 6;          // lane 0..63, part 0..3
    if (b < 400) {                          // G23 combo c23 = d2*20+d3
        int d2 = b / 20, d3 = b % 20;
#pragma unroll
        for (int i = 0; i < 3; ++i) {
            int f = t + i * 256;            // f = r2*48 + mc
            int r2 = f / 48, mc = f - r2 * 48;
            int m2 = mc >> 3, m3 = mc & 7;
            float acc = 0.f;
#pragma unroll
            for (int r3 = 0; r3 < 16; ++r3)
                acc += core2[((r2 * 20 + d2) * 6 + m2) * 16 + r3] *   // [16,20,6,16]
                       core3[(r3 * 20 + d3) * 8 + m3];                // [16,20,8,1]
            lds[f] = acc;
        }
        __syncthreads();
        {   // A01 record: 4 u32/lane; this thread writes u32 'part'
            int pp = part >> 1;             // chunk p' = 0,1 (mc 0-15 / 16-31)
            int jp = part & 1;              // k-pair within frag
            int k = ((l >> 4) << 2) + jp * 2;
            int mc = pp * 16 + (l & 15);
            g2a01[(b * 64 + l) * 4 + part] = pack2(lds[k * 48 + mc],
                                                   lds[(k + 1) * 48 + mc]);
        }
        if (part < 2) {                     // A2 record: 2 u32/lane (mc 32-47)
            int k = ((l >> 4) << 2) + part * 2;
            int mc = 32 + (l & 15);
            g2a2[(b * 64 + l) * 2 + part] = pack2(lds[k * 48 + mc],
                                                  lds[(k + 1) * 48 + mc]);
        }
    } else {                                // G01 combo c01 = d0*10+d1
        int combo = b - 400;                // 0..79
        int d0 = combo / 10, d1 = combo % 10;
        int a = t >> 4, r2 = t & 15;
        int a0 = a >> 2, m1 = a & 3;
        float acc = 0.f;
#pragma unroll
        for (int r1 = 0; r1 < 16; ++r1)
            acc += core0[(d0 * 4 + a0) * 16 + r1] *                   // [1,8,4,16]
                   core1[((r1 * 10 + d1) * 4 + m1) * 16 + r2];        // [16,10,4,16]
        lds[t] = acc;                       // lds[a*16 + r2]
        __syncthreads();
        if (part < 2) {                     // B record: 2 u32/lane
            int k = ((l >> 4) << 2) + part * 2;   // r2
            int n = l & 15;                       // a
            g1b[(combo * 64 + l) * 2 + part] = pack2(lds[n * 16 + k],
                                                     lds[n * 16 + k + 1]);
        }
    }
}

// ---- kernel B: MFMA main, zero LDS, depth-3 ring prefetch ----
struct Frag { f16x8 a01; f16x4 a2; f16x4 b; };

__device__ inline Frag load_frag(int id, int lane,
                                 const f16x8* __restrict__ g2a01,
                                 const f16x4* __restrict__ g2a2,
                                 const f16x4* __restrict__ g1b) {
    Frag f;
    int c23 = id % 400, c01 = id / 400;
    f.a01 = g2a01[c23 * 64 + lane];
    f.a2  = g2a2[c23 * 64 + lane];
    f.b   = g1b[c01 * 64 + lane];
    return f;
}

__global__ __launch_bounds__(256) void te_mfma(const int* __restrict__ x,
                                               const f16x8* __restrict__ g2a01,
                                               const f16x4* __restrict__ g2a2,
                                               const f16x4* __restrict__ g1b,
                                               float* __restrict__ out) {
    const int wave = threadIdx.x >> 6, lane = threadIdx.x & 63;
    const int tok0 = (blockIdx.x * 4 + wave) * TPW;

    int4 xa = ((const int4*)(x + tok0))[0];
    int4 xb = ((const int4*)(x + tok0))[1];
    int idxs[TPW] = {xa.x, xa.y, xa.z, xa.w, xb.x, xb.y, xb.z, xb.w};

    Frag f0 = load_frag(idxs[0], lane, g2a01, g2a2, g1b);
    Frag f1 = load_frag(idxs[1], lane, g2a01, g2a2, g1b);
    Frag f2 = load_frag(idxs[2], lane, g2a01, g2a2, g1b);

    const f32x4 z = {0.f, 0.f, 0.f, 0.f};
    float* obase = out + (size_t)tok0 * 768 + (lane & 15) * 48 + ((lane >> 4) << 2);

#pragma unroll
    for (int t = 0; t < TPW; ++t) {
        Frag f3 = f2;
        if (t + 3 < TPW)                    // depth-3 prefetch
            f3 = load_frag(idxs[t + 3], lane, g2a01, g2a2, g1b);

        f16x4 a0 = __builtin_shufflevector(f0.a01, f0.a01, 0, 1, 2, 3);
        f16x4 a1 = __builtin_shufflevector(f0.a01, f0.a01, 4, 5, 6, 7);
        f32x4 d0 = __builtin_amdgcn_mfma_f32_16x16x16f16(a0,    f0.b, z, 0, 0, 0);
        f32x4 d1 = __builtin_amdgcn_mfma_f32_16x16x16f16(a1,    f0.b, z, 0, 0, 0);
        f32x4 d2 = __builtin_amdgcn_mfma_f32_16x16x16f16(f0.a2, f0.b, z, 0, 0, 0);

        float* o = obase + t * 768;
        *(f32x4*)(o)      = d0;             // mc chunk 0
        *(f32x4*)(o + 16) = d1;             // mc chunk 1
        *(f32x4*)(o + 32) = d2;             // mc chunk 2

        f0 = f1; f1 = f2; f2 = f3;
    }
}

// ---- fallback (tiny ws): direct evaluation ----
__global__ void te_direct(const int* __restrict__ x,
                          const float* __restrict__ core0,
                          const float* __restrict__ core1,
                          const float* __restrict__ core2,
                          const float* __restrict__ core3,
                          float* __restrict__ out) {
    int tok = blockIdx.x;
    int lane = threadIdx.x;
    int idx = x[tok];
    int d0 = idx / 4000;
    int rem = idx - d0 * 4000;
    int d1 = rem / 400;
    rem -= d1 * 400;
    int d2 = rem / 20;
    int d3 = rem - d2 * 20;
    float* o = out + (size_t)tok * 768;
    for (int p = 0; p < 3; ++p) {
        int base = (p * 64 + lane) * 4;
        int a = base / 48;
        int mc = base - a * 48;
        int a0 = a >> 2, m1 = a & 3;
        float s[16];
#pragma unroll
        for (int r2 = 0; r2 < 16; ++r2) {
            float acc = 0.f;
            for (int r1 = 0; r1 < 16; ++r1)
                acc += core0[(d0 * 4 + a0) * 16 + r1] *
                       core1[((r1 * 10 + d1) * 4 + m1) * 16 + r2];
            s[r2] = acc;
        }
        float4 accv = {0.f, 0.f, 0.f, 0.f};
        float* accp = (float*)&accv;
        for (int j = 0; j < 4; ++j) {
            int mcj = mc + j;
            int m2 = mcj >> 3, m3 = mcj & 7;
            float tt = 0.f;
            for (int r2 = 0; r2 < 16; ++r2) {
                float g = 0.f;
                for (int r3 = 0; r3 < 16; ++r3)
                    g += core2[((r2 * 20 + d2) * 6 + m2) * 16 + r3] *
                         core3[(r3 * 20 + d3) * 8 + m3];
                tt += s[r2] * g;
            }
            accp[j] = tt;
        }
        *(float4*)(o + base) = accv;
    }
}

extern "C" void kernel_launch(void* const* d_in, const int* in_sizes, int n_in,
                              void* d_out, int out_size, void* d_ws, size_t ws_size,
                              hipStream_t stream) {
    const int*   x     = (const int*)d_in[0];
    const float* core0 = (const float*)d_in[1];
    const float* core1 = (const float*)d_in[2];
    const float* core2 = (const float*)d_in[3];
    const float* core3 = (const float*)d_in[4];
    float* out = (float*)d_out;

    if (ws_size >= (size_t)TBL_BYTES) {
        unsigned* g2a01 = (unsigned*)d_ws;
        unsigned* g2a2  = (unsigned*)((char*)d_ws + G2A01_BYTES);
        unsigned* g1b   = (unsigned*)((char*)d_ws + G2A01_BYTES + G2A2_BYTES);
        build_frag_tables<<<480, 256, 0, stream>>>(core0, core1, core2, core3,
                                                   g2a01, g2a2, g1b);
        // 1024 blocks x 4 waves x 8 tokens = 32768 exactly
        te_mfma<<<NBLK, 256, 0, stream>>>(x, (const f16x8*)g2a01,
                                          (const f16x4*)g2a2,
                                          (const f16x4*)g1b, out);
    } else {
        te_direct<<<NTOK, 64, 0, stream>>>(x, core0, core1, core2, core3, out);
    }
}

// Round 13
// 27.686 us; speedup vs baseline: 1.0211x; 1.0019x over previous
//
#include <hip/hip_runtime.h>

// Tensorized (tensor-train) embedding. vocab 32000 = 8*10*20*20, out 768,
// ranks (1,16,16,16,1), B = 32768 tokens, fp32 out.
//
// Per token: out[a][mc] = sum_r2 G01[c01][a][r2] * G23[c23][r2][mc]
//   (c01 = idx/400, c23 = idx%400) -- a 16x16 @ 16x48 matmul, done as
// 3x mfma_f32_16x16x16f16 (K=16 exact) on pre-swizzled f16 fragment
// tables (A = G2^T chunks, B = G1^T), transposed-tile orientation so each
// lane's 4 accs are 4 consecutive mc of one output row.
//
// R13 = R10 (best, 27.7us) + DOUBLE-BUFFERED STORE REGISTERS: even/odd
// iterations accumulate into distinct reg triples (dA/dB), moving the
// store-source WAR s_waitcnt two iterations back -> ~6 outstanding stores
// per wave instead of ~3, decoupling MFMA issue from HBM store drain.
// (R12 depth-3 prefetch was neutral -> load path fully hidden; reverted.)
//
// Fragment maps (gfx950): A[m][k]: lane l holds m=l&15, k=(l>>4)*4+j
// (j=0..3); B[k][n]: n=l&15, same k-map (A/B symmetric -> builder's
// k-permutation cancels). D[m][n]: lane l reg r: m=(l>>4)*4+r, n=l&15.

#define NTOK 32768
#define TPW  8
#define NBLK (NTOK / (4 * TPW))               // 1024
#define G2A01_BYTES (400 * 64 * 16)           // 409600
#define G2A2_BYTES  (400 * 64 * 8)            // 204800
#define G1B_BYTES   (80 * 64 * 8)             // 40960
#define TBL_BYTES   (G2A01_BYTES + G2A2_BYTES + G1B_BYTES)  // 655360

typedef _Float16 f16x4 __attribute__((ext_vector_type(4)));
typedef _Float16 f16x8 __attribute__((ext_vector_type(8)));
typedef float f32x4 __attribute__((ext_vector_type(4)));

__device__ inline unsigned pack2(float x, float y) {
    _Float16 hx = (_Float16)x, hy = (_Float16)y;
    unsigned short ux = __builtin_bit_cast(unsigned short, hx);
    unsigned short uy = __builtin_bit_cast(unsigned short, hy);
    return (unsigned)ux | ((unsigned)uy << 16);
}

// ---- kernel A: build f16 fragment tables (480 blocks) ----
__global__ __launch_bounds__(256) void build_frag_tables(const float* __restrict__ core0,
                                                         const float* __restrict__ core1,
                                                         const float* __restrict__ core2,
                                                         const float* __restrict__ core3,
                                                         unsigned* __restrict__ g2a01,
                                                         unsigned* __restrict__ g2a2,
                                                         unsigned* __restrict__ g1b) {
    __shared__ float lds[768];
    int b = blockIdx.x, t = threadIdx.x;
    int l = t & 63, part = t >> 6;          // lane 0..63, part 0..3
    if (b < 400) {                          // G23 combo c23 = d2*20+d3
        int d2 = b / 20, d3 = b % 20;
#pragma unroll
        for (int i = 0; i < 3; ++i) {
            int f = t + i * 256;            // f = r2*48 + mc
            int r2 = f / 48, mc = f - r2 * 48;
            int m2 = mc >> 3, m3 = mc & 7;
            float acc = 0.f;
#pragma unroll
            for (int r3 = 0; r3 < 16; ++r3)
                acc += core2[((r2 * 20 + d2) * 6 + m2) * 16 + r3] *   // [16,20,6,16]
                       core3[(r3 * 20 + d3) * 8 + m3];                // [16,20,8,1]
            lds[f] = acc;
        }
        __syncthreads();
        {   // A01 record: 4 u32/lane; this thread writes u32 'part'
            int pp = part >> 1;             // chunk p' = 0,1 (mc 0-15 / 16-31)
            int jp = part & 1;              // k-pair within frag
            int k = ((l >> 4) << 2) + jp * 2;
            int mc = pp * 16 + (l & 15);
            g2a01[(b * 64 + l) * 4 + part] = pack2(lds[k * 48 + mc],
                                                   lds[(k + 1) * 48 + mc]);
        }
        if (part < 2) {                     // A2 record: 2 u32/lane (mc 32-47)
            int k = ((l >> 4) << 2) + part * 2;
            int mc = 32 + (l & 15);
            g2a2[(b * 64 + l) * 2 + part] = pack2(lds[k * 48 + mc],
                                                  lds[(k + 1) * 48 + mc]);
        }
    } else {                                // G01 combo c01 = d0*10+d1
        int combo = b - 400;                // 0..79
        int d0 = combo / 10, d1 = combo % 10;
        int a = t >> 4, r2 = t & 15;
        int a0 = a >> 2, m1 = a & 3;
        float acc = 0.f;
#pragma unroll
        for (int r1 = 0; r1 < 16; ++r1)
            acc += core0[(d0 * 4 + a0) * 16 + r1] *                   // [1,8,4,16]
                   core1[((r1 * 10 + d1) * 4 + m1) * 16 + r2];        // [16,10,4,16]
        lds[t] = acc;                       // lds[a*16 + r2]
        __syncthreads();
        if (part < 2) {                     // B record: 2 u32/lane
            int k = ((l >> 4) << 2) + part * 2;   // r2
            int n = l & 15;                       // a
            g1b[(combo * 64 + l) * 2 + part] = pack2(lds[n * 16 + k],
                                                     lds[n * 16 + k + 1]);
        }
    }
}

// ---- kernel B: MFMA main, zero LDS, depth-2 prefetch, dbuf'd stores ----
struct Frag { f16x8 a01; f16x4 a2; f16x4 b; };

__device__ inline Frag load_frag(int id, int lane,
                                 const f16x8* __restrict__ g2a01,
                                 const f16x4* __restrict__ g2a2,
                                 const f16x4* __restrict__ g1b) {
    Frag f;
    int c23 = id % 400, c01 = id / 400;
    f.a01 = g2a01[c23 * 64 + lane];
    f.a2  = g2a2[c23 * 64 + lane];
    f.b   = g1b[c01 * 64 + lane];
    return f;
}

__global__ __launch_bounds__(256) void te_mfma(const int* __restrict__ x,
                                               const f16x8* __restrict__ g2a01,
                                               const f16x4* __restrict__ g2a2,
                                               const f16x4* __restrict__ g1b,
                                               float* __restrict__ out) {
    const int wave = threadIdx.x >> 6, lane = threadIdx.x & 63;
    const int tok0 = (blockIdx.x * 4 + wave) * TPW;

    int4 xa = ((const int4*)(x + tok0))[0];
    int4 xb = ((const int4*)(x + tok0))[1];
    int idxs[TPW] = {xa.x, xa.y, xa.z, xa.w, xb.x, xb.y, xb.z, xb.w};

    Frag f0 = load_frag(idxs[0], lane, g2a01, g2a2, g1b);
    Frag f1 = load_frag(idxs[1], lane, g2a01, g2a2, g1b);

    const f32x4 z = {0.f, 0.f, 0.f, 0.f};
    float* obase = out + (size_t)tok0 * 768 + (lane & 15) * 48 + ((lane >> 4) << 2);

    // two named store-register triples; t is compile-time after full unroll,
    // so the [t&1] index is static (no scratch; rule #20 safe)
    f32x4 dbuf[2][3];

#pragma unroll
    for (int t = 0; t < TPW; ++t) {
        Frag f2 = f1;
        if (t + 2 < TPW)                    // depth-2 prefetch
            f2 = load_frag(idxs[t + 2], lane, g2a01, g2a2, g1b);

        f32x4* d = dbuf[t & 1];
        f16x4 a0 = __builtin_shufflevector(f0.a01, f0.a01, 0, 1, 2, 3);
        f16x4 a1 = __builtin_shufflevector(f0.a01, f0.a01, 4, 5, 6, 7);
        d[0] = __builtin_amdgcn_mfma_f32_16x16x16f16(a0,    f0.b, z, 0, 0, 0);
        d[1] = __builtin_amdgcn_mfma_f32_16x16x16f16(a1,    f0.b, z, 0, 0, 0);
        d[2] = __builtin_amdgcn_mfma_f32_16x16x16f16(f0.a2, f0.b, z, 0, 0, 0);

        float* o = obase + t * 768;
        *(f32x4*)(o)      = d[0];           // mc chunk 0
        *(f32x4*)(o + 16) = d[1];           // mc chunk 1
        *(f32x4*)(o + 32) = d[2];           // mc chunk 2

        f0 = f1; f1 = f2;
    }
}

// ---- fallback (tiny ws): direct evaluation ----
__global__ void te_direct(const int* __restrict__ x,
                          const float* __restrict__ core0,
                          const float* __restrict__ core1,
                          const float* __restrict__ core2,
                          const float* __restrict__ core3,
                          float* __restrict__ out) {
    int tok = blockIdx.x;
    int lane = threadIdx.x;
    int idx = x[tok];
    int d0 = idx / 4000;
    int rem = idx - d0 * 4000;
    int d1 = rem / 400;
    rem -= d1 * 400;
    int d2 = rem / 20;
    int d3 = rem - d2 * 20;
    float* o = out + (size_t)tok * 768;
    for (int p = 0; p < 3; ++p) {
        int base = (p * 64 + lane) * 4;
        int a = base / 48;
        int mc = base - a * 48;
        int a0 = a >> 2, m1 = a & 3;
        float s[16];
#pragma unroll
        for (int r2 = 0; r2 < 16; ++r2) {
            float acc = 0.f;
            for (int r1 = 0; r1 < 16; ++r1)
                acc += core0[(d0 * 4 + a0) * 16 + r1] *
                       core1[((r1 * 10 + d1) * 4 + m1) * 16 + r2];
            s[r2] = acc;
        }
        float4 accv = {0.f, 0.f, 0.f, 0.f};
        float* accp = (float*)&accv;
        for (int j = 0; j < 4; ++j) {
            int mcj = mc + j;
            int m2 = mcj >> 3, m3 = mcj & 7;
            float tt = 0.f;
            for (int r2 = 0; r2 < 16; ++r2) {
                float g = 0.f;
                for (int r3 = 0; r3 < 16; ++r3)
                    g += core2[((r2 * 20 + d2) * 6 + m2) * 16 + r3] *
                         core3[(r3 * 20 + d3) * 8 + m3];
                tt += s[r2] * g;
            }
            accp[j] = tt;
        }
        *(float4*)(o + base) = accv;
    }
}

extern "C" void kernel_launch(void* const* d_in, const int* in_sizes, int n_in,
                              void* d_out, int out_size, void* d_ws, size_t ws_size,
                              hipStream_t stream) {
    const int*   x     = (const int*)d_in[0];
    const float* core0 = (const float*)d_in[1];
    const float* core1 = (const float*)d_in[2];
    const float* core2 = (const float*)d_in[3];
    const float* core3 = (const float*)d_in[4];
    float* out = (float*)d_out;

    if (ws_size >= (size_t)TBL_BYTES) {
        unsigned* g2a01 = (unsigned*)d_ws;
        unsigned* g2a2  = (unsigned*)((char*)d_ws + G2A01_BYTES);
        unsigned* g1b   = (unsigned*)((char*)d_ws + G2A01_BYTES + G2A2_BYTES);
        build_frag_tables<<<480, 256, 0, stream>>>(core0, core1, core2, core3,
                                                   g2a01, g2a2, g1b);
        // 1024 blocks x 4 waves x 8 tokens = 32768 exactly
        te_mfma<<<NBLK, 256, 0, stream>>>(x, (const f16x8*)g2a01,
                                          (const f16x4*)g2a2,
                                          (const f16x4*)g1b, out);
    } else {
        te_direct<<<NTOK, 64, 0, stream>>>(x, core0, core1, core2, core3, out);
    }
}